// Round 1
// baseline (120.050 us; speedup 1.0000x reference)
//
#include <hip/hip_runtime.h>

#define N 2048
#define BS 16
#define QCHUNK 64
#define NCHUNKS (N / QCHUNK)   // 32 chunks per batch

// Kernel 1: one block = (batch, query-chunk). 64 threads = 1 wave.
// Stage target[b] into LDS (SoA), each thread scans all 2048 targets for its
// single query point. Non-symmetric batches skip the N^2 scan.
__global__ __launch_bounds__(64) void addsloss_main(
    const float* __restrict__ target,
    const float* __restrict__ mp,
    const int* __restrict__ idx,
    const float* __restrict__ H,
    float* __restrict__ partial)
{
    __shared__ float tx[N], ty[N], tz[N];

    const int b     = blockIdx.x >> 5;    // / NCHUNKS
    const int chunk = blockIdx.x & 31;    // % NCHUNKS
    const int lane  = threadIdx.x;        // 0..63
    const int q     = chunk * QCHUNK + lane;

    const float* tb = target + (size_t)b * N * 3;
    const float* mb = mp     + (size_t)b * N * 3;
    const float* hb = H      + b * 16;

    const int  cls = idx[b];
    const bool sym = (cls >= 0) && (cls <= 3);   // isin(idx, [0,1,2,3])

    // tf = R * mp + t with R = H[:3,:3] (base = H^T so tf_e = sum_d H[e,d]*mp_d + H[e,3])
    const float m0 = mb[q * 3 + 0];
    const float m1 = mb[q * 3 + 1];
    const float m2 = mb[q * 3 + 2];
    const float fx = hb[0] * m0 + hb[1]  * m1 + hb[2]  * m2 + hb[3];
    const float fy = hb[4] * m0 + hb[5]  * m1 + hb[6]  * m2 + hb[7];
    const float fz = hb[8] * m0 + hb[9]  * m1 + hb[10] * m2 + hb[11];

    float d;
    if (sym) {
        // Stage target[b] into LDS as SoA; broadcast reads later => no bank conflicts.
        for (int i = lane; i < N; i += 64) {
            tx[i] = tb[i * 3 + 0];
            ty[i] = tb[i * 3 + 1];
            tz[i] = tb[i * 3 + 2];
        }
        __syncthreads();

        float best = 3.4e38f;
        #pragma unroll 8
        for (int r = 0; r < N; ++r) {
            const float dx = tx[r] - fx;
            const float dy = ty[r] - fy;
            const float dz = tz[r] - fz;
            float d2 = dx * dx;
            d2 = fmaf(dy, dy, d2);
            d2 = fmaf(dz, dz, d2);
            best = fminf(best, d2);
        }
        d = sqrtf(best);   // ||tf - target[argmin]|| == sqrt(min d2)
    } else {
        const float dx = fx - tb[q * 3 + 0];
        const float dy = fy - tb[q * 3 + 1];
        const float dz = fz - tb[q * 3 + 2];
        d = sqrtf(dx * dx + dy * dy + dz * dz);
    }

    // Deterministic wave-64 reduction of the 64 per-query distances.
    #pragma unroll
    for (int off = 32; off > 0; off >>= 1) d += __shfl_down(d, off);
    if (lane == 0) partial[blockIdx.x] = d;
}

// Kernel 2: per-batch deterministic reduction of the 32 chunk partials.
__global__ __launch_bounds__(64) void addsloss_reduce(
    const float* __restrict__ partial, float* __restrict__ out)
{
    const int b    = blockIdx.x;
    const int lane = threadIdx.x;
    float v = (lane < NCHUNKS) ? partial[b * NCHUNKS + lane] : 0.0f;
    #pragma unroll
    for (int off = 32; off > 0; off >>= 1) v += __shfl_down(v, off);
    if (lane == 0) out[b] = v * (1.0f / (float)N);
}

extern "C" void kernel_launch(void* const* d_in, const int* in_sizes, int n_in,
                              void* d_out, int out_size, void* d_ws, size_t ws_size,
                              hipStream_t stream) {
    const float* target = (const float*)d_in[0];   // [16, 2048, 3]
    const float* mp     = (const float*)d_in[1];   // [16, 2048, 3]
    const int*   idx    = (const int*)  d_in[2];   // [16, 1]
    const float* H      = (const float*)d_in[3];   // [16, 4, 4]
    float*       out    = (float*)d_out;           // [16]
    float*       partial = (float*)d_ws;           // BS*NCHUNKS floats

    addsloss_main<<<BS * NCHUNKS, 64, 0, stream>>>(target, mp, idx, H, partial);
    addsloss_reduce<<<BS, 64, 0, stream>>>(partial, out);
}

// Round 2
// 17.203 us; speedup vs baseline: 6.9783x; 6.9783x over previous
//
#include <hip/hip_runtime.h>

#define N 2048
#define BS 16
#define QCHUNK 64
#define NCHUNKS (N / QCHUNK)      // 32 query chunks per batch
#define WAVES 8
#define TPB (WAVES * 64)          // 512 threads
#define TGT_PER_WAVE (N / WAVES)  // 256 targets per wave
#define F4_PER_WAVE (TGT_PER_WAVE / 4)  // 64 float4 iters per component

// One block = (batch, query-chunk of 64 queries). 8 waves partition the
// target dimension; each thread owns one query and scans 256 targets with
// 4 independent min accumulators (float4 LDS broadcast reads).
__global__ __launch_bounds__(TPB) void addsloss_main(
    const float* __restrict__ target,
    const float* __restrict__ mp,
    const int* __restrict__ idx,
    const float* __restrict__ H,
    float* __restrict__ partial)
{
    __shared__ float tx[N], ty[N], tz[N];
    __shared__ float pmin[WAVES][64];

    const int b     = blockIdx.x >> 5;    // / NCHUNKS
    const int chunk = blockIdx.x & 31;    // % NCHUNKS
    const int tid   = threadIdx.x;
    const int wave  = tid >> 6;
    const int lane  = tid & 63;
    const int q     = chunk * QCHUNK + lane;

    const float* tb = target + (size_t)b * N * 3;
    const float* mb = mp     + (size_t)b * N * 3;
    const float* hb = H      + b * 16;

    const int  cls = idx[b];
    const bool sym = (cls >= 0) && (cls <= 3);

    // tf_e = sum_d H[e,d]*mp_d + H[e,3]  (every wave redundantly computes its
    // 64 queries' tf -- negligible cost)
    const float m0 = mb[q * 3 + 0];
    const float m1 = mb[q * 3 + 1];
    const float m2 = mb[q * 3 + 2];
    const float fx = hb[0] * m0 + hb[1]  * m1 + hb[2]  * m2 + hb[3];
    const float fy = hb[4] * m0 + hb[5]  * m1 + hb[6]  * m2 + hb[7];
    const float fz = hb[8] * m0 + hb[9]  * m1 + hb[10] * m2 + hb[11];

    if (sym) {
        // Cooperative SoA staging of target[b] (24 KB).
        for (int i = tid; i < N; i += TPB) {
            tx[i] = tb[i * 3 + 0];
            ty[i] = tb[i * 3 + 1];
            tz[i] = tb[i * 3 + 2];
        }
        __syncthreads();

        // This wave scans targets [wave*256, wave*256+256).
        const float4* x4 = reinterpret_cast<const float4*>(tx) + wave * F4_PER_WAVE;
        const float4* y4 = reinterpret_cast<const float4*>(ty) + wave * F4_PER_WAVE;
        const float4* z4 = reinterpret_cast<const float4*>(tz) + wave * F4_PER_WAVE;

        float b0 = 3.4e38f, b1 = 3.4e38f, b2 = 3.4e38f, b3 = 3.4e38f;
        #pragma unroll 4
        for (int j = 0; j < F4_PER_WAVE; ++j) {
            const float4 xs = x4[j];
            const float4 ys = y4[j];
            const float4 zs = z4[j];

            float dx, dy, dz, d2;
            dx = xs.x - fx; dy = ys.x - fy; dz = zs.x - fz;
            d2 = dx * dx; d2 = fmaf(dy, dy, d2); d2 = fmaf(dz, dz, d2);
            b0 = fminf(b0, d2);
            dx = xs.y - fx; dy = ys.y - fy; dz = zs.y - fz;
            d2 = dx * dx; d2 = fmaf(dy, dy, d2); d2 = fmaf(dz, dz, d2);
            b1 = fminf(b1, d2);
            dx = xs.z - fx; dy = ys.z - fy; dz = zs.z - fz;
            d2 = dx * dx; d2 = fmaf(dy, dy, d2); d2 = fmaf(dz, dz, d2);
            b2 = fminf(b2, d2);
            dx = xs.w - fx; dy = ys.w - fy; dz = zs.w - fz;
            d2 = dx * dx; d2 = fmaf(dy, dy, d2); d2 = fmaf(dz, dz, d2);
            b3 = fminf(b3, d2);
        }
        pmin[wave][lane] = fminf(fminf(b0, b1), fminf(b2, b3));
        __syncthreads();

        if (wave == 0) {
            float best = pmin[0][lane];
            #pragma unroll
            for (int w = 1; w < WAVES; ++w) best = fminf(best, pmin[w][lane]);
            float d = sqrtf(best);
            #pragma unroll
            for (int off = 32; off > 0; off >>= 1) d += __shfl_down(d, off);
            if (lane == 0) partial[blockIdx.x] = d;
        }
    } else {
        if (wave == 0) {
            const float dx = fx - tb[q * 3 + 0];
            const float dy = fy - tb[q * 3 + 1];
            const float dz = fz - tb[q * 3 + 2];
            float d = sqrtf(dx * dx + dy * dy + dz * dz);
            #pragma unroll
            for (int off = 32; off > 0; off >>= 1) d += __shfl_down(d, off);
            if (lane == 0) partial[blockIdx.x] = d;
        }
    }
}

// Kernel 2: per-batch deterministic reduction of the 32 chunk partials.
__global__ __launch_bounds__(64) void addsloss_reduce(
    const float* __restrict__ partial, float* __restrict__ out)
{
    const int b    = blockIdx.x;
    const int lane = threadIdx.x;
    float v = (lane < NCHUNKS) ? partial[b * NCHUNKS + lane] : 0.0f;
    #pragma unroll
    for (int off = 32; off > 0; off >>= 1) v += __shfl_down(v, off);
    if (lane == 0) out[b] = v * (1.0f / (float)N);
}

extern "C" void kernel_launch(void* const* d_in, const int* in_sizes, int n_in,
                              void* d_out, int out_size, void* d_ws, size_t ws_size,
                              hipStream_t stream) {
    const float* target = (const float*)d_in[0];   // [16, 2048, 3]
    const float* mp     = (const float*)d_in[1];   // [16, 2048, 3]
    const int*   idx    = (const int*)  d_in[2];   // [16, 1]
    const float* H      = (const float*)d_in[3];   // [16, 4, 4]
    float*       out    = (float*)d_out;           // [16]
    float*       partial = (float*)d_ws;           // BS*NCHUNKS floats

    addsloss_main<<<BS * NCHUNKS, TPB, 0, stream>>>(target, mp, idx, H, partial);
    addsloss_reduce<<<BS, 64, 0, stream>>>(partial, out);
}

// Round 3
// 15.879 us; speedup vs baseline: 7.5603x; 1.0834x over previous
//
#include <hip/hip_runtime.h>

#define N 2048
#define BS 16
#define QG 128             // queries per block
#define NQG (N / QG)       // 16 query groups
#define TS 256             // targets per block (tslice)
#define NTS (N / TS)       // 8 target slices
#define WAVES 4
#define TPB (WAVES * 64)   // 256 threads
#define TPW (TS / WAVES)   // 64 targets per wave
#define F4I (TPW / 4)      // 16 float4 iterations

// ws layout: wsmin[b][ts][q]  (BS * NTS * N floats = 1 MB)

// K1: one block = (batch, qgroup of 128, tslice of 256). 4 waves split the
// tslice (64 targets each); each lane owns 2 queries. Writes per-slice min-d2.
__global__ __launch_bounds__(TPB) void addsloss_k1(
    const float* __restrict__ target,
    const float* __restrict__ mp,
    const int* __restrict__ idx,
    const float* __restrict__ H,
    float* __restrict__ wsmin)
{
    __shared__ float tx[TS], ty[TS], tz[TS];
    __shared__ float pmin[WAVES][QG];

    const int bid  = blockIdx.x;
    const int b    = bid >> 7;        // / (NQG*NTS) = /128
    const int rem  = bid & 127;
    const int qg   = rem >> 3;        // / NTS
    const int ts   = rem & 7;         // % NTS
    const int tid  = threadIdx.x;
    const int wave = tid >> 6;
    const int lane = tid & 63;

    const float* tb = target + (size_t)b * N * 3;
    const float* mb = mp     + (size_t)b * N * 3;
    const float* hb = H      + b * 16;

    const int  cls = idx[b];
    const bool sym = (cls >= 0) && (cls <= 3);

    float* wrow = wsmin + ((size_t)(b * NTS + ts)) * N + qg * QG;

    if (sym) {
        // Stage this block's 256-target slice into LDS (SoA). 1 target/thread.
        {
            const int t = ts * TS + tid;
            tx[tid] = tb[t * 3 + 0];
            ty[tid] = tb[t * 3 + 1];
            tz[tid] = tb[t * 3 + 2];
        }

        // Each lane's two queries (same 128 queries across all 4 waves).
        const int q0 = qg * QG + lane;
        const int q1 = q0 + 64;
        const float m00 = mb[q0*3+0], m01 = mb[q0*3+1], m02 = mb[q0*3+2];
        const float m10 = mb[q1*3+0], m11 = mb[q1*3+1], m12 = mb[q1*3+2];
        const float f0x = hb[0]*m00 + hb[1] *m01 + hb[2] *m02 + hb[3];
        const float f0y = hb[4]*m00 + hb[5] *m01 + hb[6] *m02 + hb[7];
        const float f0z = hb[8]*m00 + hb[9] *m01 + hb[10]*m02 + hb[11];
        const float f1x = hb[0]*m10 + hb[1] *m11 + hb[2] *m12 + hb[3];
        const float f1y = hb[4]*m10 + hb[5] *m11 + hb[6] *m12 + hb[7];
        const float f1z = hb[8]*m10 + hb[9] *m11 + hb[10]*m12 + hb[11];

        __syncthreads();

        // This wave scans targets [wave*64, wave*64+64) as float4 broadcasts.
        const float4* x4 = reinterpret_cast<const float4*>(tx) + wave * F4I;
        const float4* y4 = reinterpret_cast<const float4*>(ty) + wave * F4I;
        const float4* z4 = reinterpret_cast<const float4*>(tz) + wave * F4I;

        float a0 = 3.4e38f, a1 = 3.4e38f, a2 = 3.4e38f, a3 = 3.4e38f;  // q0
        float c0 = 3.4e38f, c1 = 3.4e38f, c2 = 3.4e38f, c3 = 3.4e38f;  // q1
        #pragma unroll 4
        for (int j = 0; j < F4I; ++j) {
            const float4 xs = x4[j];
            const float4 ys = y4[j];
            const float4 zs = z4[j];
            float dx, dy, dz, d2;

            dx = xs.x - f0x; dy = ys.x - f0y; dz = zs.x - f0z;
            d2 = dx*dx; d2 = fmaf(dy,dy,d2); d2 = fmaf(dz,dz,d2); a0 = fminf(a0,d2);
            dx = xs.y - f0x; dy = ys.y - f0y; dz = zs.y - f0z;
            d2 = dx*dx; d2 = fmaf(dy,dy,d2); d2 = fmaf(dz,dz,d2); a1 = fminf(a1,d2);
            dx = xs.z - f0x; dy = ys.z - f0y; dz = zs.z - f0z;
            d2 = dx*dx; d2 = fmaf(dy,dy,d2); d2 = fmaf(dz,dz,d2); a2 = fminf(a2,d2);
            dx = xs.w - f0x; dy = ys.w - f0y; dz = zs.w - f0z;
            d2 = dx*dx; d2 = fmaf(dy,dy,d2); d2 = fmaf(dz,dz,d2); a3 = fminf(a3,d2);

            dx = xs.x - f1x; dy = ys.x - f1y; dz = zs.x - f1z;
            d2 = dx*dx; d2 = fmaf(dy,dy,d2); d2 = fmaf(dz,dz,d2); c0 = fminf(c0,d2);
            dx = xs.y - f1x; dy = ys.y - f1y; dz = zs.y - f1z;
            d2 = dx*dx; d2 = fmaf(dy,dy,d2); d2 = fmaf(dz,dz,d2); c1 = fminf(c1,d2);
            dx = xs.z - f1x; dy = ys.z - f1y; dz = zs.z - f1z;
            d2 = dx*dx; d2 = fmaf(dy,dy,d2); d2 = fmaf(dz,dz,d2); c2 = fminf(c2,d2);
            dx = xs.w - f1x; dy = ys.w - f1y; dz = zs.w - f1z;
            d2 = dx*dx; d2 = fmaf(dy,dy,d2); d2 = fmaf(dz,dz,d2); c3 = fminf(c3,d2);
        }
        pmin[wave][lane]      = fminf(fminf(a0, a1), fminf(a2, a3));
        pmin[wave][lane + 64] = fminf(fminf(c0, c1), fminf(c2, c3));
        __syncthreads();

        if (tid < QG) {
            const float m = fminf(fminf(pmin[0][tid], pmin[1][tid]),
                                  fminf(pmin[2][tid], pmin[3][tid]));
            wrow[tid] = m;
        }
    } else {
        // Non-symmetric: direct distance to same-index target. Every tslice
        // block writes the same value to its own ws cell (no races).
        if (tid < QG) {
            const int q = qg * QG + tid;
            const float m0 = mb[q*3+0], m1 = mb[q*3+1], m2 = mb[q*3+2];
            const float fx = hb[0]*m0 + hb[1] *m1 + hb[2] *m2 + hb[3];
            const float fy = hb[4]*m0 + hb[5] *m1 + hb[6] *m2 + hb[7];
            const float fz = hb[8]*m0 + hb[9] *m1 + hb[10]*m2 + hb[11];
            const float dx = fx - tb[q*3+0];
            const float dy = fy - tb[q*3+1];
            const float dz = fz - tb[q*3+2];
            wrow[tid] = dx*dx + dy*dy + dz*dz;
        }
    }
}

// K2: per batch, min over the 8 tslices, sqrt, fixed-order sum, mean.
__global__ __launch_bounds__(256) void addsloss_k2(
    const float* __restrict__ wsmin, float* __restrict__ out)
{
    __shared__ float ps[4];
    const int b    = blockIdx.x;
    const int tid  = threadIdx.x;
    const int wave = tid >> 6;
    const int lane = tid & 63;

    float s = 0.0f;
    #pragma unroll
    for (int k = 0; k < N / 256; ++k) {      // 8 queries per thread
        const int q = k * 256 + tid;
        float m = 3.4e38f;
        #pragma unroll
        for (int t = 0; t < NTS; ++t)
            m = fminf(m, wsmin[((size_t)(b * NTS + t)) * N + q]);
        s += sqrtf(m);
    }
    #pragma unroll
    for (int off = 32; off > 0; off >>= 1) s += __shfl_down(s, off);
    if (lane == 0) ps[wave] = s;
    __syncthreads();
    if (tid == 0)
        out[b] = (ps[0] + ps[1] + ps[2] + ps[3]) * (1.0f / (float)N);
}

extern "C" void kernel_launch(void* const* d_in, const int* in_sizes, int n_in,
                              void* d_out, int out_size, void* d_ws, size_t ws_size,
                              hipStream_t stream) {
    const float* target = (const float*)d_in[0];   // [16, 2048, 3]
    const float* mp     = (const float*)d_in[1];   // [16, 2048, 3]
    const int*   idx    = (const int*)  d_in[2];   // [16, 1]
    const float* H      = (const float*)d_in[3];   // [16, 4, 4]
    float*       out    = (float*)d_out;           // [16]
    float*       wsmin  = (float*)d_ws;            // BS*NTS*N floats = 1 MB

    addsloss_k1<<<BS * NQG * NTS, TPB, 0, stream>>>(target, mp, idx, H, wsmin);
    addsloss_k2<<<BS, 256, 0, stream>>>(wsmin, out);
}

// Round 4
// 15.515 us; speedup vs baseline: 7.7379x; 1.0235x over previous
//
#include <hip/hip_runtime.h>

#define N 2048
#define BS 16
#define QG 256             // queries per k1 block (4 per lane)
#define NQG (N / QG)       // 8 query groups
#define TS 256             // targets per k1 block
#define NTS (N / TS)       // 8 target slices
#define WAVES 4
#define TPB (WAVES * 64)   // 256 threads
#define TPW (TS / WAVES)   // 64 targets per wave

// ws layout: wsmin[b][ts][q]  (BS * NTS * N floats = 1 MB)
// wsmin holds  min_t ( |t|^2 - 2*tf.t )  over the block's target slice;
// k2 adds |tf|^2 back before sqrt (min(c+x) = c + min(x), c per-query const).

__global__ __launch_bounds__(TPB) void addsloss_k1(
    const float* __restrict__ target,
    const float* __restrict__ mp,
    const int* __restrict__ idx,
    const float* __restrict__ H,
    float* __restrict__ wsmin)
{
    __shared__ float4 tlds[TS];          // (x, y, z, |t|^2)
    __shared__ float  pmin[WAVES][QG];

    const int bid  = blockIdx.x;
    const int b    = bid >> 6;        // / (NQG*NTS) = /64
    const int rem  = bid & 63;
    const int qg   = rem >> 3;        // / NTS
    const int ts   = rem & 7;         // % NTS
    const int tid  = threadIdx.x;
    const int wave = tid >> 6;
    const int lane = tid & 63;

    const int  cls = idx[b];
    const bool sym = (cls >= 0) && (cls <= 3);
    if (!sym) return;                 // non-sym handled entirely in k2

    const float* tb = target + (size_t)b * N * 3;
    const float* mb = mp     + (size_t)b * N * 3;
    const float* hb = H      + b * 16;

    // Stage 256 targets as (x,y,z,|t|^2) float4, one per thread.
    {
        const int t = ts * TS + tid;
        const float x = tb[t * 3 + 0];
        const float y = tb[t * 3 + 1];
        const float z = tb[t * 3 + 2];
        tlds[tid] = make_float4(x, y, z, x * x + y * y + z * z);
    }

    // 4 queries per lane.
    float fx[4], fy[4], fz[4];
    #pragma unroll
    for (int qi = 0; qi < 4; ++qi) {
        const int q = qg * QG + qi * 64 + lane;
        const float m0 = mb[q * 3 + 0];
        const float m1 = mb[q * 3 + 1];
        const float m2 = mb[q * 3 + 2];
        fx[qi] = hb[0] * m0 + hb[1]  * m1 + hb[2]  * m2 + hb[3];
        fy[qi] = hb[4] * m0 + hb[5]  * m1 + hb[6]  * m2 + hb[7];
        fz[qi] = hb[8] * m0 + hb[9]  * m1 + hb[10] * m2 + hb[11];
    }

    __syncthreads();

    // This wave scans targets [wave*64, wave*64+64).
    const float4* t4 = &tlds[wave * TPW];

    float acc[4][4];
    #pragma unroll
    for (int qi = 0; qi < 4; ++qi)
        #pragma unroll
        for (int ti = 0; ti < 4; ++ti) acc[qi][ti] = 3.4e38f;

    for (int j = 0; j < TPW; j += 4) {
        const float4 T0 = t4[j + 0];
        const float4 T1 = t4[j + 1];
        const float4 T2 = t4[j + 2];
        const float4 T3 = t4[j + 3];
        #pragma unroll
        for (int qi = 0; qi < 4; ++qi) {
            float dot;
            dot = T0.x * fx[qi]; dot = fmaf(T0.y, fy[qi], dot); dot = fmaf(T0.z, fz[qi], dot);
            acc[qi][0] = fminf(acc[qi][0], fmaf(dot, -2.0f, T0.w));
            dot = T1.x * fx[qi]; dot = fmaf(T1.y, fy[qi], dot); dot = fmaf(T1.z, fz[qi], dot);
            acc[qi][1] = fminf(acc[qi][1], fmaf(dot, -2.0f, T1.w));
            dot = T2.x * fx[qi]; dot = fmaf(T2.y, fy[qi], dot); dot = fmaf(T2.z, fz[qi], dot);
            acc[qi][2] = fminf(acc[qi][2], fmaf(dot, -2.0f, T2.w));
            dot = T3.x * fx[qi]; dot = fmaf(T3.y, fy[qi], dot); dot = fmaf(T3.z, fz[qi], dot);
            acc[qi][3] = fminf(acc[qi][3], fmaf(dot, -2.0f, T3.w));
        }
    }

    #pragma unroll
    for (int qi = 0; qi < 4; ++qi)
        pmin[wave][qi * 64 + lane] =
            fminf(fminf(acc[qi][0], acc[qi][1]), fminf(acc[qi][2], acc[qi][3]));
    __syncthreads();

    // Combine the 4 waves, write this slice's per-query partial min.
    float* wrow = wsmin + ((size_t)(b * NTS + ts)) * N + qg * QG;
    const float m = fminf(fminf(pmin[0][tid], pmin[1][tid]),
                          fminf(pmin[2][tid], pmin[3][tid]));
    wrow[tid] = m;
}

// K2: 16 blocks x 1024 threads. Per query: recompute tf; sym -> combine the
// 8 slice-mins with +|tf|^2 and sqrt; non-sym -> direct distance. Then a
// deterministic block-wide fixed-order sum -> mean.
__global__ __launch_bounds__(1024) void addsloss_k2(
    const float* __restrict__ target,
    const float* __restrict__ mp,
    const int* __restrict__ idx,
    const float* __restrict__ H,
    const float* __restrict__ wsmin,
    float* __restrict__ out)
{
    __shared__ float ps[16];
    const int b    = blockIdx.x;
    const int tid  = threadIdx.x;
    const int wave = tid >> 6;
    const int lane = tid & 63;

    const int  cls = idx[b];
    const bool sym = (cls >= 0) && (cls <= 3);

    const float* tb = target + (size_t)b * N * 3;
    const float* mb = mp     + (size_t)b * N * 3;
    const float* hb = H      + b * 16;

    float s = 0.0f;
    #pragma unroll
    for (int k = 0; k < N / 1024; ++k) {     // 2 queries per thread
        const int q = k * 1024 + tid;
        const float m0 = mb[q * 3 + 0];
        const float m1 = mb[q * 3 + 1];
        const float m2 = mb[q * 3 + 2];
        const float fx = hb[0] * m0 + hb[1]  * m1 + hb[2]  * m2 + hb[3];
        const float fy = hb[4] * m0 + hb[5]  * m1 + hb[6]  * m2 + hb[7];
        const float fz = hb[8] * m0 + hb[9]  * m1 + hb[10] * m2 + hb[11];

        float d;
        if (sym) {
            float m = 3.4e38f;
            #pragma unroll
            for (int t = 0; t < NTS; ++t)
                m = fminf(m, wsmin[((size_t)(b * NTS + t)) * N + q]);
            const float c = fx * fx + fy * fy + fz * fz;
            d = sqrtf(fmaxf(0.0f, c + m));
        } else {
            const float dx = fx - tb[q * 3 + 0];
            const float dy = fy - tb[q * 3 + 1];
            const float dz = fz - tb[q * 3 + 2];
            d = sqrtf(dx * dx + dy * dy + dz * dz);
        }
        s += d;
    }

    #pragma unroll
    for (int off = 32; off > 0; off >>= 1) s += __shfl_down(s, off);
    if (lane == 0) ps[wave] = s;
    __syncthreads();
    if (tid == 0) {
        float tot = 0.0f;
        #pragma unroll
        for (int w = 0; w < 16; ++w) tot += ps[w];
        out[b] = tot * (1.0f / (float)N);
    }
}

extern "C" void kernel_launch(void* const* d_in, const int* in_sizes, int n_in,
                              void* d_out, int out_size, void* d_ws, size_t ws_size,
                              hipStream_t stream) {
    const float* target = (const float*)d_in[0];   // [16, 2048, 3]
    const float* mp     = (const float*)d_in[1];   // [16, 2048, 3]
    const int*   idx    = (const int*)  d_in[2];   // [16, 1]
    const float* H      = (const float*)d_in[3];   // [16, 4, 4]
    float*       out    = (float*)d_out;           // [16]
    float*       wsmin  = (float*)d_ws;            // BS*NTS*N floats = 1 MB

    addsloss_k1<<<BS * NQG * NTS, TPB, 0, stream>>>(target, mp, idx, H, wsmin);
    addsloss_k2<<<BS, 1024, 0, stream>>>(target, mp, idx, H, wsmin, out);
}

// Round 5
// 14.585 us; speedup vs baseline: 8.2311x; 1.0637x over previous
//
#include <hip/hip_runtime.h>

#define N 2048
#define BS 16
#define QG 256             // queries per k1 block (4 per lane)
#define NQG (N / QG)       // 8 query groups
#define TS 128             // targets per k1 block
#define NTS (N / TS)       // 16 target slices
#define WAVES 4
#define TPB (WAVES * 64)   // 256 threads
#define TPW (TS / WAVES)   // 32 targets per wave
#define F4I (TPW / 4)      // 8 float4 iterations

// ws layout: wsmin[b][ts][q]  (BS * NTS * N floats = 2 MB)
// wsmin holds  min_t ( |t|^2 - 2*tf.t )  over the block's 128-target slice;
// k2 adds |tf|^2 back before sqrt (min(c+x) = c + min(x)).

__global__ __launch_bounds__(TPB) void addsloss_k1(
    const float* __restrict__ target,
    const float* __restrict__ mp,
    const int* __restrict__ idx,
    const float* __restrict__ H,
    float* __restrict__ wsmin)
{
    __shared__ float4 tlds[TS];          // (x, y, z, |t|^2)
    __shared__ float  pmin[WAVES][QG];

    const int bid  = blockIdx.x;
    const int b    = bid >> 7;        // / (NQG*NTS) = /128
    const int rem  = bid & 127;
    const int qg   = rem >> 4;        // / NTS
    const int ts   = rem & 15;        // % NTS
    const int tid  = threadIdx.x;
    const int wave = tid >> 6;
    const int lane = tid & 63;

    const int  cls = idx[b];
    const bool sym = (cls >= 0) && (cls <= 3);
    if (!sym) return;                 // non-sym handled entirely in k2

    const float* tb = target + (size_t)b * N * 3;
    const float* mb = mp     + (size_t)b * N * 3;
    const float* hb = H      + b * 16;

    // Stage 128 targets as (x,y,z,|t|^2).
    if (tid < TS) {
        const int t = ts * TS + tid;
        const float x = tb[t * 3 + 0];
        const float y = tb[t * 3 + 1];
        const float z = tb[t * 3 + 2];
        tlds[tid] = make_float4(x, y, z, x * x + y * y + z * z);
    }

    // 4 queries per lane; store -2*tf so the inner op is pure fma.
    float ngx[4], ngy[4], ngz[4];
    #pragma unroll
    for (int qi = 0; qi < 4; ++qi) {
        const int q = qg * QG + qi * 64 + lane;
        const float m0 = mb[q * 3 + 0];
        const float m1 = mb[q * 3 + 1];
        const float m2 = mb[q * 3 + 2];
        ngx[qi] = -2.0f * (hb[0] * m0 + hb[1]  * m1 + hb[2]  * m2 + hb[3]);
        ngy[qi] = -2.0f * (hb[4] * m0 + hb[5]  * m1 + hb[6]  * m2 + hb[7]);
        ngz[qi] = -2.0f * (hb[8] * m0 + hb[9]  * m1 + hb[10] * m2 + hb[11]);
    }

    __syncthreads();

    // This wave scans targets [wave*32, wave*32+32).
    const float4* t4 = &tlds[wave * TPW];

    float acc[4][4];
    #pragma unroll
    for (int qi = 0; qi < 4; ++qi)
        #pragma unroll
        for (int ti = 0; ti < 4; ++ti) acc[qi][ti] = 3.4e38f;

    #pragma unroll
    for (int j = 0; j < F4I; ++j) {
        const float4 T0 = t4[j * 4 + 0];
        const float4 T1 = t4[j * 4 + 1];
        const float4 T2 = t4[j * 4 + 2];
        const float4 T3 = t4[j * 4 + 3];
        #pragma unroll
        for (int qi = 0; qi < 4; ++qi) {
            float h;
            h = T0.w; h = fmaf(ngx[qi], T0.x, h); h = fmaf(ngy[qi], T0.y, h);
            h = fmaf(ngz[qi], T0.z, h); acc[qi][0] = fminf(acc[qi][0], h);
            h = T1.w; h = fmaf(ngx[qi], T1.x, h); h = fmaf(ngy[qi], T1.y, h);
            h = fmaf(ngz[qi], T1.z, h); acc[qi][1] = fminf(acc[qi][1], h);
            h = T2.w; h = fmaf(ngx[qi], T2.x, h); h = fmaf(ngy[qi], T2.y, h);
            h = fmaf(ngz[qi], T2.z, h); acc[qi][2] = fminf(acc[qi][2], h);
            h = T3.w; h = fmaf(ngx[qi], T3.x, h); h = fmaf(ngy[qi], T3.y, h);
            h = fmaf(ngz[qi], T3.z, h); acc[qi][3] = fminf(acc[qi][3], h);
        }
    }

    #pragma unroll
    for (int qi = 0; qi < 4; ++qi)
        pmin[wave][qi * 64 + lane] =
            fminf(fminf(acc[qi][0], acc[qi][1]), fminf(acc[qi][2], acc[qi][3]));
    __syncthreads();

    // Combine the 4 waves; write this slice's per-query partial min.
    float* wrow = wsmin + ((size_t)(b * NTS + ts)) * N + qg * QG;
    const float m = fminf(fminf(pmin[0][tid], pmin[1][tid]),
                          fminf(pmin[2][tid], pmin[3][tid]));
    wrow[tid] = m;
}

// K2: 16 blocks x 512 threads; 4 consecutive queries per thread, all float4
// loads. sym: combine 16 slice-mins + |tf|^2 + sqrt; non-sym: direct distance.
__global__ __launch_bounds__(512) void addsloss_k2(
    const float* __restrict__ target,
    const float* __restrict__ mp,
    const int* __restrict__ idx,
    const float* __restrict__ H,
    const float* __restrict__ wsmin,
    float* __restrict__ out)
{
    __shared__ float ps[8];
    const int b    = blockIdx.x;
    const int tid  = threadIdx.x;
    const int wave = tid >> 6;
    const int lane = tid & 63;

    const int  cls = idx[b];
    const bool sym = (cls >= 0) && (cls <= 3);

    const float* tb = target + (size_t)b * N * 3;
    const float* mb = mp     + (size_t)b * N * 3;
    const float* hb = H      + b * 16;

    const int q0 = tid * 4;   // queries [q0, q0+4)

    // 4 queries' model points: 12 consecutive floats = 3 float4 loads.
    const float4* mq = reinterpret_cast<const float4*>(mb + (size_t)q0 * 3);
    const float4 A = mq[0], B = mq[1], C = mq[2];
    const float qx[4] = {A.x, A.w, B.z, C.y};
    const float qy[4] = {A.y, B.x, B.w, C.z};
    const float qz[4] = {A.z, B.y, C.x, C.w};

    float fx[4], fy[4], fz[4];
    #pragma unroll
    for (int i = 0; i < 4; ++i) {
        fx[i] = hb[0] * qx[i] + hb[1]  * qy[i] + hb[2]  * qz[i] + hb[3];
        fy[i] = hb[4] * qx[i] + hb[5]  * qy[i] + hb[6]  * qz[i] + hb[7];
        fz[i] = hb[8] * qx[i] + hb[9]  * qy[i] + hb[10] * qz[i] + hb[11];
    }

    float s = 0.0f;
    if (sym) {
        float4 m = make_float4(3.4e38f, 3.4e38f, 3.4e38f, 3.4e38f);
        #pragma unroll
        for (int t = 0; t < NTS; ++t) {
            const float4 v = *reinterpret_cast<const float4*>(
                wsmin + ((size_t)(b * NTS + t)) * N + q0);
            m.x = fminf(m.x, v.x); m.y = fminf(m.y, v.y);
            m.z = fminf(m.z, v.z); m.w = fminf(m.w, v.w);
        }
        const float mm[4] = {m.x, m.y, m.z, m.w};
        #pragma unroll
        for (int i = 0; i < 4; ++i) {
            const float c = fx[i] * fx[i] + fy[i] * fy[i] + fz[i] * fz[i];
            s += sqrtf(fmaxf(0.0f, c + mm[i]));
        }
    } else {
        const float4* tq = reinterpret_cast<const float4*>(tb + (size_t)q0 * 3);
        const float4 D = tq[0], E = tq[1], F = tq[2];
        const float tx[4] = {D.x, D.w, E.z, F.y};
        const float ty[4] = {D.y, E.x, E.w, F.z};
        const float tz[4] = {D.z, E.y, F.x, F.w};
        #pragma unroll
        for (int i = 0; i < 4; ++i) {
            const float dx = fx[i] - tx[i];
            const float dy = fy[i] - ty[i];
            const float dz = fz[i] - tz[i];
            s += sqrtf(dx * dx + dy * dy + dz * dz);
        }
    }

    #pragma unroll
    for (int off = 32; off > 0; off >>= 1) s += __shfl_down(s, off);
    if (lane == 0) ps[wave] = s;
    __syncthreads();
    if (tid == 0) {
        float tot = 0.0f;
        #pragma unroll
        for (int w = 0; w < 8; ++w) tot += ps[w];
        out[b] = tot * (1.0f / (float)N);
    }
}

extern "C" void kernel_launch(void* const* d_in, const int* in_sizes, int n_in,
                              void* d_out, int out_size, void* d_ws, size_t ws_size,
                              hipStream_t stream) {
    const float* target = (const float*)d_in[0];   // [16, 2048, 3]
    const float* mp     = (const float*)d_in[1];   // [16, 2048, 3]
    const int*   idx    = (const int*)  d_in[2];   // [16, 1]
    const float* H      = (const float*)d_in[3];   // [16, 4, 4]
    float*       out    = (float*)d_out;           // [16]
    float*       wsmin  = (float*)d_ws;            // BS*NTS*N floats = 2 MB

    addsloss_k1<<<BS * NQG * NTS, TPB, 0, stream>>>(target, mp, idx, H, wsmin);
    addsloss_k2<<<BS, 512, 0, stream>>>(target, mp, idx, H, wsmin, out);
}